// Round 18
// baseline (239.356 us; speedup 1.0000x reference)
//
#include <hip/hip_runtime.h>
#include <hip/hip_bf16.h>

typedef unsigned short u16;
typedef unsigned int u32;

#define T_TOK 16384
#define DIM   1024
#define NEXP  8

// ---------- workspace layout (bytes) ----------
#define XB_OFF      0
#define WB_OFF      33554432
#define CNT_OFF     50331648
#define LIST_OFF    50332160
#define SELW_OFF    50856448
#define CONTRIB_OFF 51380736
#define WS_NEED     118489600ULL

__device__ __forceinline__ u16 f2bf(float f) {
    u32 u = __float_as_uint(f);
    u += 0x7fff + ((u >> 16) & 1);   // round-to-nearest-even
    return (u16)(u >> 16);
}
__device__ __forceinline__ float bf2f(u16 u) {
    return __uint_as_float(((u32)u) << 16);
}

// Router + fused expert-weight cvt.
#define RT_PB 32

__global__ __launch_bounds__(256) void k_router(
    const float* __restrict__ x, const float* __restrict__ gw,
    const float* __restrict__ gb, float* __restrict__ logits,
    u16* __restrict__ xb, int* __restrict__ counts,
    int* __restrict__ lists, float4* __restrict__ selw,
    const float* __restrict__ ew, u16* __restrict__ wb)
{
    const int tid  = threadIdx.x;
    const int lane = tid & 63;
    const int w    = tid >> 6;

    __shared__ int   s_sel0[RT_PB], s_sel1[RT_PB];
    __shared__ int   s_lcnt[NEXP], s_gbase[NEXP];

    if (tid < NEXP) s_lcnt[tid] = 0;

    for (int i = 0; i < 8; ++i) {
        const int l = w * 8 + i;
        const int t = blockIdx.x * RT_PB + l;

        const float* xr = x + (size_t)t * DIM;
        float4 xs[4];
#pragma unroll
        for (int j = 0; j < 4; ++j)
            xs[j] = *reinterpret_cast<const float4*>(xr + (j * 64 + lane) * 4);

        float acc[NEXP];
#pragma unroll
        for (int e = 0; e < NEXP; ++e) {
            const float* gr = gw + e * DIM;
            float s = 0.f;
#pragma unroll
            for (int j = 0; j < 4; ++j) {
                float4 g = *reinterpret_cast<const float4*>(gr + (j * 64 + lane) * 4);
                s += xs[j].x * g.x + xs[j].y * g.y + xs[j].z * g.z + xs[j].w * g.w;
            }
            acc[e] = s;
        }
#pragma unroll
        for (int off = 1; off < 64; off <<= 1) {
#pragma unroll
            for (int e = 0; e < NEXP; ++e) acc[e] += __shfl_xor(acc[e], off);
        }
#pragma unroll
        for (int e = 0; e < NEXP; ++e) acc[e] += gb[e];

        int i0 = 0; float v0 = acc[0];
#pragma unroll
        for (int e = 1; e < NEXP; ++e) if (acc[e] > v0) { v0 = acc[e]; i0 = e; }
        int i1 = -1; float v1 = -3.4e38f;
#pragma unroll
        for (int e = 0; e < NEXP; ++e) if (e != i0 && acc[e] > v1) { v1 = acc[e]; i1 = e; }
        float e1  = __expf(v1 - v0);
        float inv = 1.f / (1.f + e1);
        float w0 = inv, w1 = e1 * inv;

        u16* xrow = xb + (size_t)t * DIM;
#pragma unroll
        for (int j = 0; j < 4; ++j) {
            int c = (j * 64 + lane) * 4;
            float4 v = xs[j];
            ushort4 u;
            u.x = f2bf(v.x); u.y = f2bf(v.y); u.z = f2bf(v.z); u.w = f2bf(v.w);
            *reinterpret_cast<ushort4*>(xrow + c) = u;
        }
        if (lane == 0) {
            float4 lo = make_float4(acc[0], acc[1], acc[2], acc[3]);
            float4 hi = make_float4(acc[4], acc[5], acc[6], acc[7]);
            *reinterpret_cast<float4*>(logits + (size_t)t * NEXP)     = lo;
            *reinterpret_cast<float4*>(logits + (size_t)t * NEXP + 4) = hi;
            selw[t] = make_float4(__int_as_float(i0), __int_as_float(i1), w0, w1);
            s_sel0[l] = i0; s_sel1[l] = i1;
        }
    }
    __syncthreads();

    int i0 = 0, i1 = 0, r0 = 0, r1 = 0;
    if (tid < RT_PB) {
        i0 = s_sel0[tid]; i1 = s_sel1[tid];
        r0 = atomicAdd(&s_lcnt[i0], 1);
        r1 = atomicAdd(&s_lcnt[i1], 1);
    }
    __syncthreads();
    if (tid < NEXP)
        s_gbase[tid] = atomicAdd(&counts[tid * 16], s_lcnt[tid]);
    __syncthreads();
    if (tid < RT_PB) {
        int t  = blockIdx.x * RT_PB + tid;
        lists[i0 * T_TOK + s_gbase[i0] + r0] = t * 2;
        lists[i1 * T_TOK + s_gbase[i1] + r1] = t * 2 + 1;
    }

    const int n4 = NEXP * DIM * DIM / 4;
    const int stride = gridDim.x * 256;
    for (int i = blockIdx.x * 256 + tid; i < n4; i += stride) {
        float4 v = reinterpret_cast<const float4*>(ew)[i];
        ushort4 u;
        u.x = f2bf(v.x); u.y = f2bf(v.y); u.z = f2bf(v.z); u.w = f2bf(v.w);
        reinterpret_cast<ushort4*>(wb)[i] = u;
    }
}

// ======================= grouped GEMM v11: r12 rhythm, PERSISTENT tiles.
// 128x128 tile, 4 waves (2x2), wave-tile 64x64, BK=64, 64 KiB LDS dbuf,
// 2 blocks/CU. Grid = 512 (e=bid&7 XCD-pinned, nt, mb); each block walks
// mt = mb, mb+8, ... (~4 tiles) with the K-iteration rhythm UNBROKEN
// across tiles: u=14/15 stage the next tile's K-tiles 0/1 (parity is
// preserved: 16 = 0 mod 2), the epilogue's stores overlap in-flight
// staging, and only the block prologue ever drains. Ledger per iter g:
//   LGKM0 -> LDSET(g-1) done (operands ready; buf[g&1] WAR-free)
//   VMW0  -> STAGE(g-1) done (+ iteration-old stores / list loads)
//   BAR; STAGE(g+2); LDSET(frags g+1); MFMA(g) [no internal waits].
// B staging offsets are tile-invariant; A gather offsets double-buffered
// (aoffA current / aoffN next, loaded one tile ahead).
// Proven swizzle: 128B rows, 16B-chunk slot=(chunk+row)&7 both sides.

typedef __attribute__((ext_vector_type(8))) short bf16x8;
typedef __attribute__((ext_vector_type(4))) float f32x4;

#define GLDS16(g, l) __builtin_amdgcn_global_load_lds( \
    (const __attribute__((address_space(1))) void*)(g), \
    (__attribute__((address_space(3))) void*)(l), 16, 0, 0)

#define BAR() __builtin_amdgcn_s_barrier()
#define PRIO1() __builtin_amdgcn_s_setprio(1)
#define PRIO0() __builtin_amdgcn_s_setprio(0)
#define VMW0() asm volatile("s_waitcnt vmcnt(0)" ::: "memory")
#define LGKM0() do { asm volatile("s_waitcnt lgkmcnt(0)" ::: "memory"); \
                     __builtin_amdgcn_sched_barrier(0); } while (0)

__global__ __launch_bounds__(256, 2) void k_gemm(
    const u16* __restrict__ xb, const u16* __restrict__ wb,
    const int* __restrict__ counts, const int* __restrict__ lists,
    u16* __restrict__ contrib)
{
    __shared__ char lds[65536];   // buf b*32768 | A [0,16384) | B [16384,32768)

    // persistent decode: expert -> XCD pin; 8 nt x 8 mb blocks per expert
    const int e  = blockIdx.x & 7;
    const int nt = (blockIdx.x >> 3) & 7;
    const int mb = blockIdx.x >> 6;            // 0..7
    const int cnt = counts[e * 16];
    if (mb * 128 >= cnt) return;

    const int tid  = threadIdx.x;
    const int lane = tid & 63;
    const int wid  = tid >> 6;
    const int wm   = wid >> 1;   // 0..1
    const int wn   = wid & 1;    // 0..1
    const int listbase = e * T_TOK;

    // staging: wave w instr i covers rows w*32+i*8+(lane>>3), dest slot
    // lane&7 (linear lane*16B); source chunk = ((lane&7)-row)&7.
    const int l8  = lane >> 3;
    const int cgs = ((lane & 7) - l8) & 7;
    const char* xbB = (const char*)xb;
    const char* wbB = (const char*)wb;

    u32 boff[4];
#pragma unroll
    for (int i = 0; i < 4; ++i) {
        int r = wid * 32 + i * 8 + l8;
        boff[i] = ((u32)e << 21) + (u32)(nt * 128 + r) * 2048 + (u32)cgs * 16;
    }

#define LOAD_AOFF(dst, MT) do { \
    _Pragma("unroll") for (int i = 0; i < 4; ++i) { \
        int r    = wid * 32 + i * 8 + l8; \
        int slot = (MT) * 128 + r; \
        int tok  = lists[listbase + (slot < cnt ? slot : cnt - 1)] >> 1; \
        dst[i]   = (u32)tok * 2048 + (u32)cgs * 16; \
    } } while (0)

#define STAGE_T(b, kk, AO) do { \
    _Pragma("unroll") for (int i = 0; i < 4; ++i) \
        GLDS16(xbB + AO[i] + (kk) * 128, lds + (b) * 32768 + (wid * 4 + i) * 1024); \
    _Pragma("unroll") for (int i = 0; i < 4; ++i) \
        GLDS16(wbB + boff[i] + (kk) * 128, lds + (b) * 32768 + 16384 + (wid * 4 + i) * 1024); \
} while (0)

    // read bases: row=(wm|wn)*64+mi*16+l15, chunk=kk*4+c0, slot=(chunk+l15)&7
    const int l15 = lane & 15;
    const int c0  = lane >> 4;
    const u32 ra0 = (u32)(wm * 64 + l15) * 128 + (u32)(((c0 + l15) & 7) * 16);
    const u32 ra1 = (u32)(wm * 64 + l15) * 128 + (u32)(((4 + c0 + l15) & 7) * 16);
    const u32 rb0 = 16384u + (u32)(wn * 64 + l15) * 128 + (u32)(((c0 + l15) & 7) * 16);
    const u32 rb1 = 16384u + (u32)(wn * 64 + l15) * 128 + (u32)(((4 + c0 + l15) & 7) * 16);

    bf16x8 A0[8], B0[8], A1[8], B1[8];
#define LDSET(Ad, Bd, b) do { \
    _Pragma("unroll") for (int mi = 0; mi < 4; ++mi) { \
        Ad[mi * 2 + 0] = *(const bf16x8*)(lds + (b) * 32768 + ra0 + mi * 2048); \
        Ad[mi * 2 + 1] = *(const bf16x8*)(lds + (b) * 32768 + ra1 + mi * 2048); \
    } \
    _Pragma("unroll") for (int ni = 0; ni < 4; ++ni) { \
        Bd[ni * 2 + 0] = *(const bf16x8*)(lds + (b) * 32768 + rb0 + ni * 2048); \
        Bd[ni * 2 + 1] = *(const bf16x8*)(lds + (b) * 32768 + rb1 + ni * 2048); \
    } \
} while (0)

    f32x4 acc[4][4];
#pragma unroll
    for (int mi = 0; mi < 4; ++mi)
#pragma unroll
        for (int ni = 0; ni < 4; ++ni) acc[mi][ni] = (f32x4)0.f;

#define MFMAS(As, Bs) do { \
    _Pragma("unroll") for (int kk = 0; kk < 2; ++kk) \
    _Pragma("unroll") for (int mi = 0; mi < 4; ++mi) \
    _Pragma("unroll") for (int ni = 0; ni < 4; ++ni) \
        acc[mi][ni] = __builtin_amdgcn_mfma_f32_16x16x32_bf16( \
            As[mi * 2 + kk], Bs[ni * 2 + kk], acc[mi][ni], 0, 0, 0); \
} while (0)

    int mtCur = mb;
    u32 aoffA[4], aoffN[4];
    LOAD_AOFF(aoffA, mtCur);

    // block prologue (only drain in the kernel)
    STAGE_T(0, 0, aoffA); STAGE_T(1, 1, aoffA);
    VMW0(); BAR();
    LDSET(A0, B0, 0);

    bool first = true;
    while (true) {
        const int  mtNext  = mtCur + 8;
        const bool hasNext = mtNext * 128 < cnt;
        if (hasNext) LOAD_AOFF(aoffN, mtNext);

#pragma unroll
        for (int u = 0; u < 16; ++u) {
            LGKM0();
            if (!first || u > 0) VMW0();
            BAR();
            if (u <= 13) {
                STAGE_T(u & 1, u + 2, aoffA);
            } else if (hasNext) {
                STAGE_T(u & 1, u - 14, aoffN);   // next tile k0 (u=14) / k1 (u=15)
            }
            if (u < 15) {
                if ((u & 1) == 0) LDSET(A1, B1, 1); else LDSET(A0, B0, 0);
            } else if (hasNext) {
                LDSET(A0, B0, 0);                // next tile k0 frags
            }
            PRIO1();
            if ((u & 1) == 0) MFMAS(A0, B0); else MFMAS(A1, B1);
            PRIO0();
        }

        // epilogue for mtCur: C/D layout col=lane&15, row=(lane>>4)*4+reg.
        // Stores overlap next tile's in-flight staging (no drain).
        {
            const int rbase = c0 * 4;
            const int cbase = nt * 128 + wn * 64 + l15;
#pragma unroll
            for (int mi = 0; mi < 4; ++mi) {
#pragma unroll
                for (int r = 0; r < 4; ++r) {
                    int slot = mtCur * 128 + wm * 64 + mi * 16 + rbase + r;
                    if (slot < cnt) {
                        int lv = lists[listbase + slot];
                        u16* crow = contrib + (size_t)lv * DIM + cbase;
#pragma unroll
                        for (int ni = 0; ni < 4; ++ni)
                            crow[ni * 16] = f2bf(acc[mi][ni][r]);
                    }
                }
            }
        }

        if (!hasNext) break;
        first = false;
        mtCur = mtNext;
#pragma unroll
        for (int i = 0; i < 4; ++i) aoffA[i] = aoffN[i];
#pragma unroll
        for (int mi = 0; mi < 4; ++mi)
#pragma unroll
            for (int ni = 0; ni < 4; ++ni) acc[mi][ni] = (f32x4)0.f;
    }
}

// out[t] = w0*(c0 + b[e0]) + w1*(c1 + b[e1]); 4 tokens/block
__global__ __launch_bounds__(256) void k_combine(
    const u16* __restrict__ contrib, const float4* __restrict__ selw,
    const float* __restrict__ eb, float* __restrict__ out)
{
    const int lane = threadIdx.x & 63;
    const int t    = blockIdx.x * 4 + (threadIdx.x >> 6);
    float4 sw = selw[t];
    const int e0 = __float_as_int(sw.x);
    const int e1 = __float_as_int(sw.y);
    const float w0 = sw.z, w1 = sw.w;
    const u16* c0 = contrib + (size_t)(t * 2) * DIM;
    const u16* c1 = c0 + DIM;
    const float* b0 = eb + e0 * DIM;
    const float* b1 = eb + e1 * DIM;
    float* orow = out + (size_t)t * DIM;
#pragma unroll
    for (int j = 0; j < 2; ++j) {
        const int c = (j * 64 + lane) * 8;
        uint4 u0 = *reinterpret_cast<const uint4*>(c0 + c);
        uint4 u1 = *reinterpret_cast<const uint4*>(c1 + c);
        const u16* p0 = (const u16*)&u0;
        const u16* p1 = (const u16*)&u1;
#pragma unroll
        for (int h = 0; h < 2; ++h) {
            float4 bb0 = *reinterpret_cast<const float4*>(b0 + c + h * 4);
            float4 bb1 = *reinterpret_cast<const float4*>(b1 + c + h * 4);
            float4 o;
            o.x = w0 * (bf2f(p0[h*4+0]) + bb0.x) + w1 * (bf2f(p1[h*4+0]) + bb1.x);
            o.y = w0 * (bf2f(p0[h*4+1]) + bb0.y) + w1 * (bf2f(p1[h*4+1]) + bb1.y);
            o.z = w0 * (bf2f(p0[h*4+2]) + bb0.z) + w1 * (bf2f(p1[h*4+2]) + bb1.z);
            o.w = w0 * (bf2f(p0[h*4+3]) + bb0.w) + w1 * (bf2f(p1[h*4+3]) + bb1.w);
            *reinterpret_cast<float4*>(orow + c + h * 4) = o;
        }
    }
}

// fallback: bias-init + atomic GEMM when ws too small for contrib
__global__ __launch_bounds__(256) void k_bias(
    const float4* __restrict__ selw, const float* __restrict__ eb,
    float* __restrict__ out)
{
    const int lane = threadIdx.x & 63;
    const int t    = blockIdx.x * 4 + (threadIdx.x >> 6);
    float4 sw = selw[t];
    const float* b0 = eb + __float_as_int(sw.x) * DIM;
    const float* b1 = eb + __float_as_int(sw.y) * DIM;
    float* orow = out + (size_t)t * DIM;
#pragma unroll
    for (int j = 0; j < 4; ++j) {
        int c = (j * 64 + lane) * 4;
        float4 f0 = *reinterpret_cast<const float4*>(b0 + c);
        float4 f1 = *reinterpret_cast<const float4*>(b1 + c);
        float4 o;
        o.x = sw.z * f0.x + sw.w * f1.x;
        o.y = sw.z * f0.y + sw.w * f1.y;
        o.z = sw.z * f0.z + sw.w * f1.z;
        o.w = sw.z * f0.w + sw.w * f1.w;
        *reinterpret_cast<float4*>(orow + c) = o;
    }
}

__global__ __launch_bounds__(256) void k_gemm_atomic(
    const u16* __restrict__ xb, const u16* __restrict__ wb,
    const int* __restrict__ counts, const int* __restrict__ lists,
    const float4* __restrict__ selw, float* __restrict__ out)
{
    __shared__ u16 ldsA[128 * 64];
    __shared__ u16 ldsB[128 * 64];
    const int bid = blockIdx.x;
    const int e   = bid >> 10;
    const int mt  = (bid >> 3) & 127;
    const int nt  = bid & 7;
    const int cnt = counts[e * 16];
    if (mt * 128 >= cnt) return;
    const int tid  = threadIdx.x;
    const int lane = tid & 63;
    const int wid  = tid >> 6;
    const int wr   = wid >> 1, wc = wid & 1;
    const int srow = tid >> 3;
    const int skc  = (tid & 7) * 8;
    const int listbase = e * T_TOK;
    int tokA[4];
#pragma unroll
    for (int i = 0; i < 4; ++i) {
        int slot = mt * 128 + i * 32 + srow;
        tokA[i] = lists[listbase + (slot < cnt ? slot : cnt - 1)] >> 1;
    }
    const size_t wbase = ((size_t)e << 20) + (size_t)(nt * 128) * DIM;
    f32x4 acc[4][4];
#pragma unroll
    for (int mi = 0; mi < 4; ++mi)
#pragma unroll
        for (int ni = 0; ni < 4; ++ni) acc[mi][ni] = (f32x4)0.f;
    for (int k0 = 0; k0 < DIM; k0 += 64) {
        uint4 ra[4], rb[4];
#pragma unroll
        for (int i = 0; i < 4; ++i) {
            ra[i] = *reinterpret_cast<const uint4*>(xb + (size_t)tokA[i] * DIM + k0 + skc);
            rb[i] = *reinterpret_cast<const uint4*>(wb + wbase + (size_t)(i * 32 + srow) * DIM + k0 + skc);
        }
        __syncthreads();
#pragma unroll
        for (int i = 0; i < 4; ++i) {
            *reinterpret_cast<uint4*>(ldsA + (i * 32 + srow) * 64 + skc) = ra[i];
            *reinterpret_cast<uint4*>(ldsB + (i * 32 + srow) * 64 + skc) = rb[i];
        }
        __syncthreads();
#pragma unroll
        for (int ks = 0; ks < 2; ++ks) {
            const int kof = ks * 32 + (lane >> 4) * 8;
            bf16x8 af[4], bfr[4];
#pragma unroll
            for (int mi = 0; mi < 4; ++mi)
                af[mi] = *reinterpret_cast<const bf16x8*>(ldsA + (wr * 64 + mi * 16 + (lane & 15)) * 64 + kof);
#pragma unroll
            for (int ni = 0; ni < 4; ++ni)
                bfr[ni] = *reinterpret_cast<const bf16x8*>(ldsB + (wc * 64 + ni * 16 + (lane & 15)) * 64 + kof);
#pragma unroll
            for (int mi = 0; mi < 4; ++mi)
#pragma unroll
                for (int ni = 0; ni < 4; ++ni)
                    acc[mi][ni] = __builtin_amdgcn_mfma_f32_16x16x32_bf16(af[mi], bfr[ni], acc[mi][ni], 0, 0, 0);
        }
        __syncthreads();
    }
    const int rbase = (lane >> 4) * 4;
    const int cbase = nt * 128 + wc * 64 + (lane & 15);
#pragma unroll
    for (int mi = 0; mi < 4; ++mi) {
#pragma unroll
        for (int r = 0; r < 4; ++r) {
            int slot = mt * 128 + wr * 64 + mi * 16 + rbase + r;
            if (slot < cnt) {
                int lv = lists[listbase + slot];
                int tok = lv >> 1;
                float4 sw = selw[tok];
                float wgt = (lv & 1) ? sw.w : sw.z;
                float* orow = out + (size_t)tok * DIM + cbase;
#pragma unroll
                for (int ni = 0; ni < 4; ++ni)
                    atomicAdd(orow + ni * 16, acc[mi][ni][r] * wgt);
            }
        }
    }
}

extern "C" void kernel_launch(void* const* d_in, const int* in_sizes, int n_in,
                              void* d_out, int out_size, void* d_ws, size_t ws_size,
                              hipStream_t stream) {
    const float* x  = (const float*)d_in[0];
    const float* gw = (const float*)d_in[1];
    const float* gb = (const float*)d_in[2];
    const float* ew = (const float*)d_in[3];
    const float* eb = (const float*)d_in[4];

    float* out    = (float*)d_out;
    float* logits = out + (size_t)T_TOK * DIM;

    char*   ws      = (char*)d_ws;
    u16*    xb      = (u16*)(ws + XB_OFF);
    u16*    wb      = (u16*)(ws + WB_OFF);
    int*    counts  = (int*)(ws + CNT_OFF);
    int*    lists   = (int*)(ws + LIST_OFF);
    float4* selw    = (float4*)(ws + SELW_OFF);
    u16*    contrib = (u16*)(ws + CONTRIB_OFF);

    hipMemsetAsync((void*)(ws + CNT_OFF), 0, 512, stream);
    k_router<<<T_TOK / RT_PB, 256, 0, stream>>>(x, gw, gb, logits, xb, counts,
                                                lists, selw, ew, wb);

    if (ws_size >= WS_NEED) {
        k_gemm<<<512, 256, 0, stream>>>(xb, wb, counts, lists, contrib);
        k_combine<<<T_TOK / 4, 256, 0, stream>>>(contrib, selw, eb, out);
    } else {
        k_bias<<<T_TOK / 4, 256, 0, stream>>>(selw, eb, out);
        k_gemm_atomic<<<NEXP * 128 * 8, 256, 0, stream>>>(xb, wb, counts, lists, selw, out);
    }
}

// Round 19
// 154.582 us; speedup vs baseline: 1.5484x; 1.5484x over previous
//
#include <hip/hip_runtime.h>
#include <hip/hip_bf16.h>

typedef unsigned short u16;
typedef unsigned int u32;

#define T_TOK 16384
#define DIM   1024
#define NEXP  8

// ---------- workspace layout (bytes) ----------
#define XB_OFF      0
#define WB_OFF      33554432
#define CNT_OFF     50331648
#define LIST_OFF    50332160
#define SELW_OFF    50856448
#define CONTRIB_OFF 51380736
#define WS_NEED     118489600ULL

__device__ __forceinline__ u16 f2bf(float f) {
    u32 u = __float_as_uint(f);
    u += 0x7fff + ((u >> 16) & 1);   // round-to-nearest-even
    return (u16)(u >> 16);
}
__device__ __forceinline__ float bf2f(u16 u) {
    return __uint_as_float(((u32)u) << 16);
}

// Router + fused expert-weight cvt.
#define RT_PB 32

__global__ __launch_bounds__(256) void k_router(
    const float* __restrict__ x, const float* __restrict__ gw,
    const float* __restrict__ gb, float* __restrict__ logits,
    u16* __restrict__ xb, int* __restrict__ counts,
    int* __restrict__ lists, float4* __restrict__ selw,
    const float* __restrict__ ew, u16* __restrict__ wb)
{
    const int tid  = threadIdx.x;
    const int lane = tid & 63;
    const int w    = tid >> 6;

    __shared__ int   s_sel0[RT_PB], s_sel1[RT_PB];
    __shared__ int   s_lcnt[NEXP], s_gbase[NEXP];

    if (tid < NEXP) s_lcnt[tid] = 0;

    for (int i = 0; i < 8; ++i) {
        const int l = w * 8 + i;
        const int t = blockIdx.x * RT_PB + l;

        const float* xr = x + (size_t)t * DIM;
        float4 xs[4];
#pragma unroll
        for (int j = 0; j < 4; ++j)
            xs[j] = *reinterpret_cast<const float4*>(xr + (j * 64 + lane) * 4);

        float acc[NEXP];
#pragma unroll
        for (int e = 0; e < NEXP; ++e) {
            const float* gr = gw + e * DIM;
            float s = 0.f;
#pragma unroll
            for (int j = 0; j < 4; ++j) {
                float4 g = *reinterpret_cast<const float4*>(gr + (j * 64 + lane) * 4);
                s += xs[j].x * g.x + xs[j].y * g.y + xs[j].z * g.z + xs[j].w * g.w;
            }
            acc[e] = s;
        }
#pragma unroll
        for (int off = 1; off < 64; off <<= 1) {
#pragma unroll
            for (int e = 0; e < NEXP; ++e) acc[e] += __shfl_xor(acc[e], off);
        }
#pragma unroll
        for (int e = 0; e < NEXP; ++e) acc[e] += gb[e];

        int i0 = 0; float v0 = acc[0];
#pragma unroll
        for (int e = 1; e < NEXP; ++e) if (acc[e] > v0) { v0 = acc[e]; i0 = e; }
        int i1 = -1; float v1 = -3.4e38f;
#pragma unroll
        for (int e = 0; e < NEXP; ++e) if (e != i0 && acc[e] > v1) { v1 = acc[e]; i1 = e; }
        float e1  = __expf(v1 - v0);
        float inv = 1.f / (1.f + e1);
        float w0 = inv, w1 = e1 * inv;

        u16* xrow = xb + (size_t)t * DIM;
#pragma unroll
        for (int j = 0; j < 4; ++j) {
            int c = (j * 64 + lane) * 4;
            float4 v = xs[j];
            ushort4 u;
            u.x = f2bf(v.x); u.y = f2bf(v.y); u.z = f2bf(v.z); u.w = f2bf(v.w);
            *reinterpret_cast<ushort4*>(xrow + c) = u;
        }
        if (lane == 0) {
            float4 lo = make_float4(acc[0], acc[1], acc[2], acc[3]);
            float4 hi = make_float4(acc[4], acc[5], acc[6], acc[7]);
            *reinterpret_cast<float4*>(logits + (size_t)t * NEXP)     = lo;
            *reinterpret_cast<float4*>(logits + (size_t)t * NEXP + 4) = hi;
            selw[t] = make_float4(__int_as_float(i0), __int_as_float(i1), w0, w1);
            s_sel0[l] = i0; s_sel1[l] = i1;
        }
    }
    __syncthreads();

    int i0 = 0, i1 = 0, r0 = 0, r1 = 0;
    if (tid < RT_PB) {
        i0 = s_sel0[tid]; i1 = s_sel1[tid];
        r0 = atomicAdd(&s_lcnt[i0], 1);
        r1 = atomicAdd(&s_lcnt[i1], 1);
    }
    __syncthreads();
    if (tid < NEXP)
        s_gbase[tid] = atomicAdd(&counts[tid * 16], s_lcnt[tid]);
    __syncthreads();
    if (tid < RT_PB) {
        int t  = blockIdx.x * RT_PB + tid;
        lists[i0 * T_TOK + s_gbase[i0] + r0] = t * 2;
        lists[i1 * T_TOK + s_gbase[i1] + r1] = t * 2 + 1;
    }

    const int n4 = NEXP * DIM * DIM / 4;
    const int stride = gridDim.x * 256;
    for (int i = blockIdx.x * 256 + tid; i < n4; i += stride) {
        float4 v = reinterpret_cast<const float4*>(ew)[i];
        ushort4 u;
        u.x = f2bf(v.x); u.y = f2bf(v.y); u.z = f2bf(v.z); u.w = f2bf(v.w);
        reinterpret_cast<ushort4*>(wb)[i] = u;
    }
}

// ======================= grouped GEMM (r12 champion, final):
// register-fragment double-buffer. 128x128 tile, 4 waves (2x2), wave-tile
// 64x64, BK=64, 64 KiB LDS dbuf -> 2 blocks/CU (2 waves/SIMD). Per K-tile
// iteration u (all waits prove ITERATION-OLD ops; MFMA has no waits):
//   LGKM0 -> LDSET(u-1) done (operands ready; buf WAR-free)
//   VMW0  -> STAGE(u-1) done (tile u+1 readable)
//   BAR; STAGE(buf[u&1], tile u+2); LDSET(next frags, buf[(u+1)&1]); MFMA.
// Proven swizzle: 128B rows, 16B-chunk slot=(chunk+row)&7 both sides.
// Design-space bracketing (r13-r18): BK=32 rows -> bank conflicts; 64x128
// wave-tile @2w/SIMD -> VGPR spill; @1w/SIMD -> -28% (no co-residency);
// persistent tiles -> 3.3x FETCH (L2 working-set blowup). This config is
// the feasible optimum of {regfile, LDS port, co-residency, swizzle, L2}.

typedef __attribute__((ext_vector_type(8))) short bf16x8;
typedef __attribute__((ext_vector_type(4))) float f32x4;

#define GLDS16(g, l) __builtin_amdgcn_global_load_lds( \
    (const __attribute__((address_space(1))) void*)(g), \
    (__attribute__((address_space(3))) void*)(l), 16, 0, 0)

#define BAR() __builtin_amdgcn_s_barrier()
#define PRIO1() __builtin_amdgcn_s_setprio(1)
#define PRIO0() __builtin_amdgcn_s_setprio(0)
#define VMW0() asm volatile("s_waitcnt vmcnt(0)" ::: "memory")
#define LGKM0() do { asm volatile("s_waitcnt lgkmcnt(0)" ::: "memory"); \
                     __builtin_amdgcn_sched_barrier(0); } while (0)

__global__ __launch_bounds__(256, 2) void k_gemm(
    const u16* __restrict__ xb, const u16* __restrict__ wb,
    const int* __restrict__ counts, const int* __restrict__ lists,
    u16* __restrict__ contrib)
{
    __shared__ char lds[65536];   // buf b*32768 | A [0,16384) | B [16384,32768)

    // expert->XCD pinning: XCD x owns expert x's 1024 slots (128 mt x 8 nt)
    const int bid = (blockIdx.x & 7) * 1024 + (blockIdx.x >> 3);
    const int e   = bid >> 10;
    const int mt  = (bid >> 3) & 127;
    const int nt  = bid & 7;
    const int cnt = counts[e * 16];
    if (mt * 128 >= cnt) return;

    const int tid  = threadIdx.x;
    const int lane = tid & 63;
    const int wid  = tid >> 6;
    const int wm   = wid >> 1;   // 0..1
    const int wn   = wid & 1;    // 0..1
    const int listbase = e * T_TOK;

    // staging: wave w instr i covers rows w*32+i*8+(lane>>3), dest slot
    // lane&7 (linear lane*16B); source chunk = ((lane&7)-row)&7.
    const int l8  = lane >> 3;
    const int cgs = ((lane & 7) - l8) & 7;
    const char* xbB = (const char*)xb;
    const char* wbB = (const char*)wb;
    u32 aoff[4], boff[4];
#pragma unroll
    for (int i = 0; i < 4; ++i) {
        int r    = wid * 32 + i * 8 + l8;
        int slot = mt * 128 + r;
        int tok  = lists[listbase + (slot < cnt ? slot : cnt - 1)] >> 1;
        aoff[i]  = (u32)tok * 2048 + (u32)cgs * 16;
        boff[i]  = ((u32)e << 21) + (u32)(nt * 128 + r) * 2048 + (u32)cgs * 16;
    }

#define STAGE(b, t) do { \
    _Pragma("unroll") for (int i = 0; i < 4; ++i) \
        GLDS16(xbB + aoff[i] + (t) * 128, lds + (b) * 32768 + (wid * 4 + i) * 1024); \
    _Pragma("unroll") for (int i = 0; i < 4; ++i) \
        GLDS16(wbB + boff[i] + (t) * 128, lds + (b) * 32768 + 16384 + (wid * 4 + i) * 1024); \
} while (0)

    // read bases: row=(wm|wn)*64+mi*16+l15, chunk=kk*4+c0, slot=(chunk+l15)&7
    const int l15 = lane & 15;
    const int c0  = lane >> 4;
    const u32 ra0 = (u32)(wm * 64 + l15) * 128 + (u32)(((c0 + l15) & 7) * 16);
    const u32 ra1 = (u32)(wm * 64 + l15) * 128 + (u32)(((4 + c0 + l15) & 7) * 16);
    const u32 rb0 = 16384u + (u32)(wn * 64 + l15) * 128 + (u32)(((c0 + l15) & 7) * 16);
    const u32 rb1 = 16384u + (u32)(wn * 64 + l15) * 128 + (u32)(((4 + c0 + l15) & 7) * 16);

    bf16x8 A0[8], B0[8], A1[8], B1[8];
#define LDSET(Ad, Bd, b) do { \
    _Pragma("unroll") for (int mi = 0; mi < 4; ++mi) { \
        Ad[mi * 2 + 0] = *(const bf16x8*)(lds + (b) * 32768 + ra0 + mi * 2048); \
        Ad[mi * 2 + 1] = *(const bf16x8*)(lds + (b) * 32768 + ra1 + mi * 2048); \
    } \
    _Pragma("unroll") for (int ni = 0; ni < 4; ++ni) { \
        Bd[ni * 2 + 0] = *(const bf16x8*)(lds + (b) * 32768 + rb0 + ni * 2048); \
        Bd[ni * 2 + 1] = *(const bf16x8*)(lds + (b) * 32768 + rb1 + ni * 2048); \
    } \
} while (0)

    f32x4 acc[4][4];
#pragma unroll
    for (int mi = 0; mi < 4; ++mi)
#pragma unroll
        for (int ni = 0; ni < 4; ++ni) acc[mi][ni] = (f32x4)0.f;

#define MFMAS(As, Bs) do { \
    _Pragma("unroll") for (int kk = 0; kk < 2; ++kk) \
    _Pragma("unroll") for (int mi = 0; mi < 4; ++mi) \
    _Pragma("unroll") for (int ni = 0; ni < 4; ++ni) \
        acc[mi][ni] = __builtin_amdgcn_mfma_f32_16x16x32_bf16( \
            As[mi * 2 + kk], Bs[ni * 2 + kk], acc[mi][ni], 0, 0, 0); \
} while (0)

#define ITER(U, Ac, Bc, An, Bn) do { \
    LGKM0(); \
    if ((U) >= 1) VMW0(); \
    BAR(); \
    if ((U) <= 13) STAGE((U) & 1, (U) + 2); \
    if ((U) <= 14) LDSET(An, Bn, ((U) + 1) & 1); \
    PRIO1(); MFMAS(Ac, Bc); PRIO0(); \
} while (0)

    // prologue: stage tiles 0,1; preload frags(0)
    STAGE(0, 0); STAGE(1, 1);
    VMW0(); BAR();
    LDSET(A0, B0, 0);

#pragma unroll
    for (int h = 0; h < 8; ++h) {
        ITER(2 * h,     A0, B0, A1, B1);
        ITER(2 * h + 1, A1, B1, A0, B0);
    }

    // epilogue: C/D layout col=lane&15, row=(lane>>4)*4+reg
    const int rbase = c0 * 4;
    const int cbase = nt * 128 + wn * 64 + l15;
#pragma unroll
    for (int mi = 0; mi < 4; ++mi) {
#pragma unroll
        for (int r = 0; r < 4; ++r) {
            int slot = mt * 128 + wm * 64 + mi * 16 + rbase + r;
            if (slot < cnt) {
                int lv = lists[listbase + slot];
                u16* crow = contrib + (size_t)lv * DIM + cbase;
#pragma unroll
                for (int ni = 0; ni < 4; ++ni)
                    crow[ni * 16] = f2bf(acc[mi][ni][r]);
            }
        }
    }
}

// out[t] = w0*(c0 + b[e0]) + w1*(c1 + b[e1]); 4 tokens/block
__global__ __launch_bounds__(256) void k_combine(
    const u16* __restrict__ contrib, const float4* __restrict__ selw,
    const float* __restrict__ eb, float* __restrict__ out)
{
    const int lane = threadIdx.x & 63;
    const int t    = blockIdx.x * 4 + (threadIdx.x >> 6);
    float4 sw = selw[t];
    const int e0 = __float_as_int(sw.x);
    const int e1 = __float_as_int(sw.y);
    const float w0 = sw.z, w1 = sw.w;
    const u16* c0 = contrib + (size_t)(t * 2) * DIM;
    const u16* c1 = c0 + DIM;
    const float* b0 = eb + e0 * DIM;
    const float* b1 = eb + e1 * DIM;
    float* orow = out + (size_t)t * DIM;
#pragma unroll
    for (int j = 0; j < 2; ++j) {
        const int c = (j * 64 + lane) * 8;
        uint4 u0 = *reinterpret_cast<const uint4*>(c0 + c);
        uint4 u1 = *reinterpret_cast<const uint4*>(c1 + c);
        const u16* p0 = (const u16*)&u0;
        const u16* p1 = (const u16*)&u1;
#pragma unroll
        for (int h = 0; h < 2; ++h) {
            float4 bb0 = *reinterpret_cast<const float4*>(b0 + c + h * 4);
            float4 bb1 = *reinterpret_cast<const float4*>(b1 + c + h * 4);
            float4 o;
            o.x = w0 * (bf2f(p0[h*4+0]) + bb0.x) + w1 * (bf2f(p1[h*4+0]) + bb1.x);
            o.y = w0 * (bf2f(p0[h*4+1]) + bb0.y) + w1 * (bf2f(p1[h*4+1]) + bb1.y);
            o.z = w0 * (bf2f(p0[h*4+2]) + bb0.z) + w1 * (bf2f(p1[h*4+2]) + bb1.z);
            o.w = w0 * (bf2f(p0[h*4+3]) + bb0.w) + w1 * (bf2f(p1[h*4+3]) + bb1.w);
            *reinterpret_cast<float4*>(orow + c + h * 4) = o;
        }
    }
}

// fallback: bias-init + atomic GEMM when ws too small for contrib
__global__ __launch_bounds__(256) void k_bias(
    const float4* __restrict__ selw, const float* __restrict__ eb,
    float* __restrict__ out)
{
    const int lane = threadIdx.x & 63;
    const int t    = blockIdx.x * 4 + (threadIdx.x >> 6);
    float4 sw = selw[t];
    const float* b0 = eb + __float_as_int(sw.x) * DIM;
    const float* b1 = eb + __float_as_int(sw.y) * DIM;
    float* orow = out + (size_t)t * DIM;
#pragma unroll
    for (int j = 0; j < 4; ++j) {
        int c = (j * 64 + lane) * 4;
        float4 f0 = *reinterpret_cast<const float4*>(b0 + c);
        float4 f1 = *reinterpret_cast<const float4*>(b1 + c);
        float4 o;
        o.x = sw.z * f0.x + sw.w * f1.x;
        o.y = sw.z * f0.y + sw.w * f1.y;
        o.z = sw.z * f0.z + sw.w * f1.z;
        o.w = sw.z * f0.w + sw.w * f1.w;
        *reinterpret_cast<float4*>(orow + c) = o;
    }
}

__global__ __launch_bounds__(256) void k_gemm_atomic(
    const u16* __restrict__ xb, const u16* __restrict__ wb,
    const int* __restrict__ counts, const int* __restrict__ lists,
    const float4* __restrict__ selw, float* __restrict__ out)
{
    __shared__ u16 ldsA[128 * 64];
    __shared__ u16 ldsB[128 * 64];
    const int bid = blockIdx.x;
    const int e   = bid >> 10;
    const int mt  = (bid >> 3) & 127;
    const int nt  = bid & 7;
    const int cnt = counts[e * 16];
    if (mt * 128 >= cnt) return;
    const int tid  = threadIdx.x;
    const int lane = tid & 63;
    const int wid  = tid >> 6;
    const int wr   = wid >> 1, wc = wid & 1;
    const int srow = tid >> 3;
    const int skc  = (tid & 7) * 8;
    const int listbase = e * T_TOK;
    int tokA[4];
#pragma unroll
    for (int i = 0; i < 4; ++i) {
        int slot = mt * 128 + i * 32 + srow;
        tokA[i] = lists[listbase + (slot < cnt ? slot : cnt - 1)] >> 1;
    }
    const size_t wbase = ((size_t)e << 20) + (size_t)(nt * 128) * DIM;
    f32x4 acc[4][4];
#pragma unroll
    for (int mi = 0; mi < 4; ++mi)
#pragma unroll
        for (int ni = 0; ni < 4; ++ni) acc[mi][ni] = (f32x4)0.f;
    for (int k0 = 0; k0 < DIM; k0 += 64) {
        uint4 ra[4], rb[4];
#pragma unroll
        for (int i = 0; i < 4; ++i) {
            ra[i] = *reinterpret_cast<const uint4*>(xb + (size_t)tokA[i] * DIM + k0 + skc);
            rb[i] = *reinterpret_cast<const uint4*>(wb + wbase + (size_t)(i * 32 + srow) * DIM + k0 + skc);
        }
        __syncthreads();
#pragma unroll
        for (int i = 0; i < 4; ++i) {
            *reinterpret_cast<uint4*>(ldsA + (i * 32 + srow) * 64 + skc) = ra[i];
            *reinterpret_cast<uint4*>(ldsB + (i * 32 + srow) * 64 + skc) = rb[i];
        }
        __syncthreads();
#pragma unroll
        for (int ks = 0; ks < 2; ++ks) {
            const int kof = ks * 32 + (lane >> 4) * 8;
            bf16x8 af[4], bfr[4];
#pragma unroll
            for (int mi = 0; mi < 4; ++mi)
                af[mi] = *reinterpret_cast<const bf16x8*>(ldsA + (wr * 64 + mi * 16 + (lane & 15)) * 64 + kof);
#pragma unroll
            for (int ni = 0; ni < 4; ++ni)
                bfr[ni] = *reinterpret_cast<const bf16x8*>(ldsB + (wc * 64 + ni * 16 + (lane & 15)) * 64 + kof);
#pragma unroll
            for (int mi = 0; mi < 4; ++mi)
#pragma unroll
                for (int ni = 0; ni < 4; ++ni)
                    acc[mi][ni] = __builtin_amdgcn_mfma_f32_16x16x32_bf16(af[mi], bfr[ni], acc[mi][ni], 0, 0, 0);
        }
        __syncthreads();
    }
    const int rbase = (lane >> 4) * 4;
    const int cbase = nt * 128 + wc * 64 + (lane & 15);
#pragma unroll
    for (int mi = 0; mi < 4; ++mi) {
#pragma unroll
        for (int r = 0; r < 4; ++r) {
            int slot = mt * 128 + wr * 64 + mi * 16 + rbase + r;
            if (slot < cnt) {
                int lv = lists[listbase + slot];
                int tok = lv >> 1;
                float4 sw = selw[tok];
                float wgt = (lv & 1) ? sw.w : sw.z;
                float* orow = out + (size_t)tok * DIM + cbase;
#pragma unroll
                for (int ni = 0; ni < 4; ++ni)
                    atomicAdd(orow + ni * 16, acc[mi][ni][r] * wgt);
            }
        }
    }
}

extern "C" void kernel_launch(void* const* d_in, const int* in_sizes, int n_in,
                              void* d_out, int out_size, void* d_ws, size_t ws_size,
                              hipStream_t stream) {
    const float* x  = (const float*)d_in[0];
    const float* gw = (const float*)d_in[1];
    const float* gb = (const float*)d_in[2];
    const float* ew = (const float*)d_in[3];
    const float* eb = (const float*)d_in[4];

    float* out    = (float*)d_out;
    float* logits = out + (size_t)T_TOK * DIM;

    char*   ws      = (char*)d_ws;
    u16*    xb      = (u16*)(ws + XB_OFF);
    u16*    wb      = (u16*)(ws + WB_OFF);
    int*    counts  = (int*)(ws + CNT_OFF);
    int*    lists   = (int*)(ws + LIST_OFF);
    float4* selw    = (float4*)(ws + SELW_OFF);
    u16*    contrib = (u16*)(ws + CONTRIB_OFF);

    hipMemsetAsync((void*)(ws + CNT_OFF), 0, 512, stream);
    k_router<<<T_TOK / RT_PB, 256, 0, stream>>>(x, gw, gb, logits, xb, counts,
                                                lists, selw, ew, wb);

    if (ws_size >= WS_NEED) {
        k_gemm<<<NEXP * 128 * 8, 256, 0, stream>>>(xb, wb, counts, lists, contrib);
        k_combine<<<T_TOK / 4, 256, 0, stream>>>(contrib, selw, eb, out);
    } else {
        k_bias<<<T_TOK / 4, 256, 0, stream>>>(selw, eb, out);
        k_gemm_atomic<<<NEXP * 128 * 8, 256, 0, stream>>>(xb, wb, counts, lists, selw, out);
    }
}